// Round 5
// baseline (114.288 us; speedup 1.0000x reference)
//
#include <hip/hip_runtime.h>
#include <math.h>

typedef _Float16 half8 __attribute__((ext_vector_type(8)));
typedef _Float16 half4v __attribute__((ext_vector_type(4)));
typedef float floatx4 __attribute__((ext_vector_type(4)));

// ---------------------------------------------------------------------------
// Prep: hih = (f16)(E@W1a + b1), hjh = (f16)(E@W1b); W2/W3 pre-swizzled into
// MFMA fragment order. blocks 0..255: four (b,s) rows each (256 thr:
// t<128 -> hi half, t>=128 -> hj half; 4 accumulators share each W1 load).
// block 256: W2frag. block 257: W3frag.
// ---------------------------------------------------------------------------
__global__ __launch_bounds__(256) void prep_kernel(
    const float* __restrict__ E,
    const float* __restrict__ W1,
    const float* __restrict__ b1,
    const float* __restrict__ W2,
    const float* __restrict__ W3,
    _Float16* __restrict__ hih,
    _Float16* __restrict__ hjh,
    _Float16* __restrict__ W2frag,
    _Float16* __restrict__ W3frag)
{
    const int blk = blockIdx.x;
    const int t = threadIdx.x;
    if (blk < 256) {
        __shared__ float sE[4][128];
        const int r0 = blk * 4;
        for (int e = t; e < 512; e += 256)
            sE[e >> 7][e & 127] = E[r0*128 + e];
        __syncthreads();
        const int half = t >> 7;       // 0: hi (with b1), 1: hj
        const int k = t & 127;
        float a0 = half ? 0.f : b1[k];
        float a1 = a0, a2 = a0, a3 = a0;
        const float* w1col = &W1[half*128*128 + k];
        #pragma unroll 8
        for (int d = 0; d < 128; ++d) {
            const float w = w1col[d*128];
            a0 = fmaf(sE[0][d], w, a0);
            a1 = fmaf(sE[1][d], w, a1);
            a2 = fmaf(sE[2][d], w, a2);
            a3 = fmaf(sE[3][d], w, a3);
        }
        _Float16* dst = half ? hjh : hih;
        dst[(r0+0)*128 + k] = (_Float16)a0;
        dst[(r0+1)*128 + k] = (_Float16)a1;
        dst[(r0+2)*128 + k] = (_Float16)a2;
        dst[(r0+3)*128 + k] = (_Float16)a3;
    } else if (blk == 256) {
        // A-frag order: frag g=((wr*4+nt)*4+ks), lane l, elem q holds
        // W2t[n][k]=W2[k][n], n=64*wr+16*nt+(l&15), k=ks*32+(l>>4)*8+q
        for (int e = t; e < 16384; e += 256) {
            int q = e & 7, l = (e >> 3) & 63, g = e >> 9;
            int wr = g >> 4, nt = (g >> 2) & 3, ks = g & 3;
            int row = 64*wr + 16*nt + (l & 15);
            int k = ks*32 + (l >> 4)*8 + q;
            W2frag[e] = (_Float16)W2[k*128 + row];
        }
    } else {
        // B-frag order: frag ks, lane l, elem q holds W3[k][n2],
        // n2=l&15, k=ks*32+(l>>4)*8+q
        for (int e = t; e < 2048; e += 256) {
            int q = e & 7, l = (e >> 3) & 63, ks = e >> 9;
            int k = ks*32 + (l >> 4)*8 + q;
            W3frag[e] = (_Float16)W3[k*16 + (l & 15)];
        }
    }
}

// ---------------------------------------------------------------------------
// Main: one block = (b, i0..i0+7, j0..j0+127). 512 blocks = exactly one
// scheduling round at 2 blocks/CU. hj tile staged ONCE into XOR-swizzled LDS;
// W2/W3 fragments, b2 vectors register-resident across all 8 i's. Phase
// pipeline per i: [H2-write, prefetches] barrier [GEMM2(i) + GEMM1(i+1) +
// epilogue(i)] barrier — the fat region gives the scheduler 72 MFMA + LDS +
// VMEM of independent work to absorb barrier/LDS latency at 2 waves/SIMD.
// Nontemporal output stores keep the 33.5MB stream from evicting L2 operands.
// ---------------------------------------------------------------------------
__device__ __forceinline__ int swz(int row, int chunk) {
    // half-index of the 16B chunk base inside a [128][128] f16 tile
    return row*128 + ((chunk ^ (row & 7)) << 3);
}

__global__ __launch_bounds__(256, 2) void main_kernel(
    const _Float16* __restrict__ hih,
    const _Float16* __restrict__ hjh,
    const _Float16* __restrict__ W2frag,
    const _Float16* __restrict__ W3frag,
    const float* __restrict__ b2,
    const float* __restrict__ b3,
    const float* __restrict__ temps,
    const int* __restrict__ mask,
    float* __restrict__ out)
{
    __shared__ __align__(16) _Float16 sHJ[128 * 128];  // raw hj tile (persists)
    __shared__ __align__(16) _Float16 sH2[128 * 128];  // per-i H2

    const int tid = threadIdx.x;
    const int bid = blockIdx.x;
    const int b  = bid >> 8;                 // 2 x 64 x 4 = 512 blocks
    const int i0 = ((bid >> 2) & 63) << 3;   // 8 i's per block
    const int j0 = (bid & 3) << 7;

    const int lane = tid & 63;
    const int wave = tid >> 6;
    const int wr = wave >> 1;   // n-strip
    const int wc = wave & 1;    // m-strip (j)
    const int lr = lane & 15;
    const int lq = lane >> 4;
    const int m0 = 32*wave;

    const half8 zero8 = {};
    const _Float16* hirow = &hih[(b*512 + i0)*128];
    const _Float16* hjbase = &hjh[(b*512 + j0)*128];
    const half8* w2v = (const half8*)W2frag;
    const half8* w3v = (const half8*)W3frag;

    // W2 A-fragments straight to registers (16 x b128, L2-hot), once per block
    half8 aW[4][4];
    #pragma unroll
    for (int nt = 0; nt < 4; ++nt)
        #pragma unroll
        for (int ks = 0; ks < 4; ++ks)
            aW[nt][ks] = w2v[((wr*4 + nt)*4 + ks)*64 + lane];

    // W3 B-fragments, once per block
    half8 w3F[4];
    #pragma unroll
    for (int ks = 0; ks < 4; ++ks)
        w3F[ks] = w3v[ks*64 + lane];

    // b2 bias vectors (n-dependent only), once per block
    float4 bv[4];
    #pragma unroll
    for (int nt = 0; nt < 4; ++nt)
        bv[nt] = *(const float4*)&b2[64*wr + 16*nt + 4*lq];

    // hi fragments for i0
    half8 hiF[4];
    #pragma unroll
    for (int ks = 0; ks < 4; ++ks)
        hiF[ks] = *(const half8*)&hirow[ks*32 + lq*8];

    // epilogue constants
    const int n2 = lr;
    const float tempv = temps[n2];
    const float b3v = b3[n2];

    // Stage raw hj tile once: 2048 16B-chunks, lane-contiguous, swizzled dest
    #pragma unroll
    for (int kk = 0; kk < 8; ++kk) {
        const int c = kk*256 + tid;       // chunk id
        const int row = c >> 4, col = c & 15;
        half8 v = *(const half8*)&hjbase[row*128 + col*8];
        *(half8*)&sHJ[swz(row, col)] = v;
    }
    __syncthreads();

    // GEMM1': D[n][m] = sum_k W2[k][n] * relu(hi[k]+hj[m][k])
    floatx4 acc[4][4];
    auto run_gemm1 = [&]() {
        #pragma unroll
        for (int nt = 0; nt < 4; ++nt)
            #pragma unroll
            for (int mt = 0; mt < 4; ++mt)
                acc[nt][mt] = (floatx4){};
        #pragma unroll
        for (int ks = 0; ks < 4; ++ks) {
            half8 bF[4];
            #pragma unroll
            for (int mt = 0; mt < 4; ++mt) {
                const int m = 64*wc + 16*mt + lr;
                half8 hj8 = *(const half8*)&sHJ[swz(m, ks*4 + lq)];
                bF[mt] = __builtin_elementwise_max(hiF[ks] + hj8, zero8);
            }
            #pragma unroll
            for (int nt = 0; nt < 4; ++nt)
                #pragma unroll
                for (int mt = 0; mt < 4; ++mt)
                    acc[nt][mt] = __builtin_amdgcn_mfma_f32_16x16x32_f16(
                        aW[nt][ks], bF[mt], acc[nt][mt], 0, 0, 0);
        }
    };

    run_gemm1();   // ii = 0

    for (int ii = 0; ii < 8; ++ii) {
        const int i = i0 + ii;

        // Phase 1 (thin): H2[m][n] = relu(D + b2[n]) -> swizzled LDS (b64)
        #pragma unroll
        for (int nt = 0; nt < 4; ++nt) {
            const int nb = 64*wr + 16*nt + 4*lq;
            #pragma unroll
            for (int mt = 0; mt < 4; ++mt) {
                const int m = 64*wc + 16*mt + lr;
                floatx4 v = acc[nt][mt];
                half4v o;
                o[0] = (_Float16)fmaxf(v[0] + bv[nt].x, 0.f);
                o[1] = (_Float16)fmaxf(v[1] + bv[nt].y, 0.f);
                o[2] = (_Float16)fmaxf(v[2] + bv[nt].z, 0.f);
                o[3] = (_Float16)fmaxf(v[3] + bv[nt].w, 0.f);
                *(half4v*)&sH2[swz(m, nb >> 3) + (nb & 7)] = o;
            }
        }

        // Prefetch next i's hi fragments + this i's mask (latency hides
        // under the LDS-write drain + barrier)
        {
            const _Float16* hin = &hirow[((ii < 7) ? (ii + 1) : ii)*128];
            #pragma unroll
            for (int ks = 0; ks < 4; ++ks)
                hiF[ks] = *(const half8*)&hin[ks*32 + lq*8];
        }
        const int* mrow = &mask[(b*512 + i)*512];
        int4 mk0 = *(const int4*)&mrow[j0 + m0 + 4*lq];
        int4 mk1 = *(const int4*)&mrow[j0 + m0 + 16 + 4*lq];
        __syncthreads();

        // Phase 2 (fat): GEMM2(ii) + GEMM1(ii+1) + epilogue(ii)
        floatx4 acc2[2] = {};
        #pragma unroll
        for (int ks = 0; ks < 4; ++ks) {
            half8 a0v = *(const half8*)&sH2[swz(m0 + lr, ks*4 + lq)];
            half8 a1v = *(const half8*)&sH2[swz(m0 + 16 + lr, ks*4 + lq)];
            acc2[0] = __builtin_amdgcn_mfma_f32_16x16x32_f16(a0v, w3F[ks], acc2[0], 0, 0, 0);
            acc2[1] = __builtin_amdgcn_mfma_f32_16x16x32_f16(a1v, w3F[ks], acc2[1], 0, 0, 0);
        }

        if (ii < 7) run_gemm1();   // next i's GEMM1 overlaps GEMM2/epilogue

        // Epilogue: bias = (comp + b3)*temp, mask -> -inf, nontemporal stores
        // (clang ext-vector floatx4: builtin rejects HIP_vector_type float4)
        float* outp = &out[(((b*16 + n2)*512) + i)*512];
        {
            const int j = j0 + m0 + 4*lq;
            floatx4 v = acc2[0];
            floatx4 res;
            res[0] = mk0.x ? (v[0] + b3v)*tempv : -INFINITY;
            res[1] = mk0.y ? (v[1] + b3v)*tempv : -INFINITY;
            res[2] = mk0.z ? (v[2] + b3v)*tempv : -INFINITY;
            res[3] = mk0.w ? (v[3] + b3v)*tempv : -INFINITY;
            __builtin_nontemporal_store(res, (floatx4*)&outp[j]);
        }
        {
            const int j = j0 + m0 + 16 + 4*lq;
            floatx4 v = acc2[1];
            floatx4 res;
            res[0] = mk1.x ? (v[0] + b3v)*tempv : -INFINITY;
            res[1] = mk1.y ? (v[1] + b3v)*tempv : -INFINITY;
            res[2] = mk1.z ? (v[2] + b3v)*tempv : -INFINITY;
            res[3] = mk1.w ? (v[3] + b3v)*tempv : -INFINITY;
            __builtin_nontemporal_store(res, (floatx4*)&outp[j]);
        }

        if (ii < 7) __syncthreads();   // all waves done reading sH2 before overwrite
    }
}

extern "C" void kernel_launch(void* const* d_in, const int* in_sizes, int n_in,
                              void* d_out, int out_size, void* d_ws, size_t ws_size,
                              hipStream_t stream)
{
    const float* E     = (const float*)d_in[0];
    const int* mask    = (const int*)d_in[1];
    const float* W1    = (const float*)d_in[2];
    const float* b1    = (const float*)d_in[3];
    const float* W2    = (const float*)d_in[4];
    const float* b2    = (const float*)d_in[5];
    const float* W3    = (const float*)d_in[6];
    const float* b3    = (const float*)d_in[7];
    const float* temps = (const float*)d_in[8];

    char* ws = (char*)d_ws;
    _Float16* hih = (_Float16*)ws;                       // 1024*128 f16 = 256KB
    _Float16* hjh = (_Float16*)(ws + 262144);            // 256KB
    _Float16* W2f = (_Float16*)(ws + 524288);            // 32KB
    _Float16* W3f = W2f + 16384;                         // 4KB

    prep_kernel<<<258, 256, 0, stream>>>(E, W1, b1, W2, W3, hih, hjh, W2f, W3f);
    main_kernel<<<512, 256, 0, stream>>>(hih, hjh, W2f, W3f, b2, b3, temps, mask,
                                         (float*)d_out);
}

// Round 6
// 110.513 us; speedup vs baseline: 1.0342x; 1.0342x over previous
//
#include <hip/hip_runtime.h>
#include <math.h>

typedef _Float16 half8 __attribute__((ext_vector_type(8)));
typedef _Float16 half4v __attribute__((ext_vector_type(4)));
typedef float floatx4 __attribute__((ext_vector_type(4)));

// ---------------------------------------------------------------------------
// Prep: hih = (f16)(E@W1a + b1), hjh = (f16)(E@W1b); W2/W3 pre-swizzled into
// MFMA fragment order. blocks 0..255: four (b,s) rows each (256 thr:
// t<128 -> hi half, t>=128 -> hj half; 4 accumulators share each W1 load).
// block 256: W2frag. block 257: W3frag.
// ---------------------------------------------------------------------------
__global__ __launch_bounds__(256) void prep_kernel(
    const float* __restrict__ E,
    const float* __restrict__ W1,
    const float* __restrict__ b1,
    const float* __restrict__ W2,
    const float* __restrict__ W3,
    _Float16* __restrict__ hih,
    _Float16* __restrict__ hjh,
    _Float16* __restrict__ W2frag,
    _Float16* __restrict__ W3frag)
{
    const int blk = blockIdx.x;
    const int t = threadIdx.x;
    if (blk < 256) {
        __shared__ float sE[4][128];
        const int r0 = blk * 4;
        for (int e = t; e < 512; e += 256)
            sE[e >> 7][e & 127] = E[r0*128 + e];
        __syncthreads();
        const int half = t >> 7;       // 0: hi (with b1), 1: hj
        const int k = t & 127;
        float a0 = half ? 0.f : b1[k];
        float a1 = a0, a2 = a0, a3 = a0;
        const float* w1col = &W1[half*128*128 + k];
        #pragma unroll 8
        for (int d = 0; d < 128; ++d) {
            const float w = w1col[d*128];
            a0 = fmaf(sE[0][d], w, a0);
            a1 = fmaf(sE[1][d], w, a1);
            a2 = fmaf(sE[2][d], w, a2);
            a3 = fmaf(sE[3][d], w, a3);
        }
        _Float16* dst = half ? hjh : hih;
        dst[(r0+0)*128 + k] = (_Float16)a0;
        dst[(r0+1)*128 + k] = (_Float16)a1;
        dst[(r0+2)*128 + k] = (_Float16)a2;
        dst[(r0+3)*128 + k] = (_Float16)a3;
    } else if (blk == 256) {
        // A-frag order: frag g=((wr*4+nt)*4+ks), lane l, elem q holds
        // W2t[n][k]=W2[k][n], n=64*wr+16*nt+(l&15), k=ks*32+(l>>4)*8+q
        for (int e = t; e < 16384; e += 256) {
            int q = e & 7, l = (e >> 3) & 63, g = e >> 9;
            int wr = g >> 4, nt = (g >> 2) & 3, ks = g & 3;
            int row = 64*wr + 16*nt + (l & 15);
            int k = ks*32 + (l >> 4)*8 + q;
            W2frag[e] = (_Float16)W2[k*128 + row];
        }
    } else {
        // B-frag order: frag ks, lane l, elem q holds W3[k][n2],
        // n2=l&15, k=ks*32+(l>>4)*8+q
        for (int e = t; e < 2048; e += 256) {
            int q = e & 7, l = (e >> 3) & 63, ks = e >> 9;
            int k = ks*32 + (l >> 4)*8 + q;
            W3frag[e] = (_Float16)W3[k*16 + (l & 15)];
        }
    }
}

// ---------------------------------------------------------------------------
// Main: one block = (b, i0..i0+7, j0..j0+127). 512 blocks = one scheduling
// round at 2 blocks/CU. hj tile staged ONCE into XOR-swizzled LDS; W2/W3
// fragments, b2 vectors register-resident across all 8 i's. Per-i schedule is
// the simple R4 form (no acc live across barriers — R5's pipelining raised
// register pressure and was net-negative): GEMM1 -> H2 write -> barrier ->
// GEMM2 -> epilogue -> barrier. Nontemporal output stores keep the 33.5MB
// stream from evicting L2-resident operands.
// ---------------------------------------------------------------------------
__device__ __forceinline__ int swz(int row, int chunk) {
    // half-index of the 16B chunk base inside a [128][128] f16 tile
    return row*128 + ((chunk ^ (row & 7)) << 3);
}

__global__ __launch_bounds__(256, 2) void main_kernel(
    const _Float16* __restrict__ hih,
    const _Float16* __restrict__ hjh,
    const _Float16* __restrict__ W2frag,
    const _Float16* __restrict__ W3frag,
    const float* __restrict__ b2,
    const float* __restrict__ b3,
    const float* __restrict__ temps,
    const int* __restrict__ mask,
    float* __restrict__ out)
{
    __shared__ __align__(16) _Float16 sHJ[128 * 128];  // raw hj tile (persists)
    __shared__ __align__(16) _Float16 sH2[128 * 128];  // per-i H2

    const int tid = threadIdx.x;
    const int bid = blockIdx.x;
    const int b  = bid >> 8;                 // 2 x 64 x 4 = 512 blocks
    const int i0 = ((bid >> 2) & 63) << 3;   // 8 i's per block
    const int j0 = (bid & 3) << 7;

    const int lane = tid & 63;
    const int wave = tid >> 6;
    const int wr = wave >> 1;   // n-strip
    const int wc = wave & 1;    // m-strip (j)
    const int lr = lane & 15;
    const int lq = lane >> 4;
    const int m0 = 32*wave;

    const half8 zero8 = {};
    const _Float16* hirow = &hih[(b*512 + i0)*128];
    const _Float16* hjbase = &hjh[(b*512 + j0)*128];
    const half8* w2v = (const half8*)W2frag;
    const half8* w3v = (const half8*)W3frag;

    // W2 A-fragments straight to registers (16 x b128, L2-hot), once per block
    half8 aW[4][4];
    #pragma unroll
    for (int nt = 0; nt < 4; ++nt)
        #pragma unroll
        for (int ks = 0; ks < 4; ++ks)
            aW[nt][ks] = w2v[((wr*4 + nt)*4 + ks)*64 + lane];

    // W3 B-fragments, once per block
    half8 w3F[4];
    #pragma unroll
    for (int ks = 0; ks < 4; ++ks)
        w3F[ks] = w3v[ks*64 + lane];

    // b2 bias vectors (n-dependent only), once per block
    float4 bv[4];
    #pragma unroll
    for (int nt = 0; nt < 4; ++nt)
        bv[nt] = *(const float4*)&b2[64*wr + 16*nt + 4*lq];

    // hi fragments for i0
    half8 hiF[4];
    #pragma unroll
    for (int ks = 0; ks < 4; ++ks)
        hiF[ks] = *(const half8*)&hirow[ks*32 + lq*8];

    // epilogue constants
    const int n2 = lr;
    const float tempv = temps[n2];
    const float b3v = b3[n2];

    // Stage raw hj tile once: 2048 16B-chunks, lane-contiguous, swizzled dest
    #pragma unroll
    for (int kk = 0; kk < 8; ++kk) {
        const int c = kk*256 + tid;       // chunk id
        const int row = c >> 4, col = c & 15;
        half8 v = *(const half8*)&hjbase[row*128 + col*8];
        *(half8*)&sHJ[swz(row, col)] = v;
    }
    __syncthreads();

    for (int ii = 0; ii < 8; ++ii) {
        const int i = i0 + ii;

        // GEMM1': D[n][m] = sum_k W2[k][n] * relu(hi[k]+hj[m][k])
        floatx4 acc[4][4] = {};
        #pragma unroll
        for (int ks = 0; ks < 4; ++ks) {
            half8 bF[4];
            #pragma unroll
            for (int mt = 0; mt < 4; ++mt) {
                const int m = 64*wc + 16*mt + lr;
                half8 hj8 = *(const half8*)&sHJ[swz(m, ks*4 + lq)];
                bF[mt] = __builtin_elementwise_max(hiF[ks] + hj8, zero8);
            }
            #pragma unroll
            for (int nt = 0; nt < 4; ++nt)
                #pragma unroll
                for (int mt = 0; mt < 4; ++mt)
                    acc[nt][mt] = __builtin_amdgcn_mfma_f32_16x16x32_f16(
                        aW[nt][ks], bF[mt], acc[nt][mt], 0, 0, 0);
        }

        // Prefetch next i's hi fragments (hides L2 latency under H2+barrier)
        {
            const _Float16* hin = &hirow[((ii < 7) ? (ii + 1) : ii)*128];
            #pragma unroll
            for (int ks = 0; ks < 4; ++ks)
                hiF[ks] = *(const half8*)&hin[ks*32 + lq*8];
        }

        // H2[m][n] = relu(D + b2[n]); lane's 4 regs = 4 consecutive n -> b64
        #pragma unroll
        for (int nt = 0; nt < 4; ++nt) {
            const int nb = 64*wr + 16*nt + 4*lq;
            #pragma unroll
            for (int mt = 0; mt < 4; ++mt) {
                const int m = 64*wc + 16*mt + lr;
                floatx4 v = acc[nt][mt];
                half4v o;
                o[0] = (_Float16)fmaxf(v[0] + bv[nt].x, 0.f);
                o[1] = (_Float16)fmaxf(v[1] + bv[nt].y, 0.f);
                o[2] = (_Float16)fmaxf(v[2] + bv[nt].z, 0.f);
                o[3] = (_Float16)fmaxf(v[3] + bv[nt].w, 0.f);
                *(half4v*)&sH2[swz(m, nb >> 3) + (nb & 7)] = o;
            }
        }

        // Prefetch mask while LDS settles
        const int* mrow = &mask[(b*512 + i)*512];
        int4 mk0 = *(const int4*)&mrow[j0 + m0 + 4*lq];
        int4 mk1 = *(const int4*)&mrow[j0 + m0 + 16 + 4*lq];
        __syncthreads();

        // GEMM2: D2[m][n2] = sum_n H2[m][n] * W3[n][n2]
        floatx4 acc2[2] = {};
        #pragma unroll
        for (int ks = 0; ks < 4; ++ks) {
            half8 a0v = *(const half8*)&sH2[swz(m0 + lr, ks*4 + lq)];
            half8 a1v = *(const half8*)&sH2[swz(m0 + 16 + lr, ks*4 + lq)];
            acc2[0] = __builtin_amdgcn_mfma_f32_16x16x32_f16(a0v, w3F[ks], acc2[0], 0, 0, 0);
            acc2[1] = __builtin_amdgcn_mfma_f32_16x16x32_f16(a1v, w3F[ks], acc2[1], 0, 0, 0);
        }

        // Epilogue: bias = (comp + b3)*temp, mask -> -inf, nontemporal stores
        // (clang ext-vector floatx4: builtin rejects HIP_vector_type float4)
        float* outp = &out[(((b*16 + n2)*512) + i)*512];
        {
            const int j = j0 + m0 + 4*lq;
            floatx4 v = acc2[0];
            floatx4 res;
            res[0] = mk0.x ? (v[0] + b3v)*tempv : -INFINITY;
            res[1] = mk0.y ? (v[1] + b3v)*tempv : -INFINITY;
            res[2] = mk0.z ? (v[2] + b3v)*tempv : -INFINITY;
            res[3] = mk0.w ? (v[3] + b3v)*tempv : -INFINITY;
            __builtin_nontemporal_store(res, (floatx4*)&outp[j]);
        }
        {
            const int j = j0 + m0 + 16 + 4*lq;
            floatx4 v = acc2[1];
            floatx4 res;
            res[0] = mk1.x ? (v[0] + b3v)*tempv : -INFINITY;
            res[1] = mk1.y ? (v[1] + b3v)*tempv : -INFINITY;
            res[2] = mk1.z ? (v[2] + b3v)*tempv : -INFINITY;
            res[3] = mk1.w ? (v[3] + b3v)*tempv : -INFINITY;
            __builtin_nontemporal_store(res, (floatx4*)&outp[j]);
        }

        if (ii < 7) __syncthreads();   // all waves done reading sH2 before overwrite
    }
}

extern "C" void kernel_launch(void* const* d_in, const int* in_sizes, int n_in,
                              void* d_out, int out_size, void* d_ws, size_t ws_size,
                              hipStream_t stream)
{
    const float* E     = (const float*)d_in[0];
    const int* mask    = (const int*)d_in[1];
    const float* W1    = (const float*)d_in[2];
    const float* b1    = (const float*)d_in[3];
    const float* W2    = (const float*)d_in[4];
    const float* b2    = (const float*)d_in[5];
    const float* W3    = (const float*)d_in[6];
    const float* b3    = (const float*)d_in[7];
    const float* temps = (const float*)d_in[8];

    char* ws = (char*)d_ws;
    _Float16* hih = (_Float16*)ws;                       // 1024*128 f16 = 256KB
    _Float16* hjh = (_Float16*)(ws + 262144);            // 256KB
    _Float16* W2f = (_Float16*)(ws + 524288);            // 32KB
    _Float16* W3f = W2f + 16384;                         // 4KB

    prep_kernel<<<258, 256, 0, stream>>>(E, W1, b1, W2, W3, hih, hjh, W2f, W3f);
    main_kernel<<<512, 256, 0, stream>>>(hih, hjh, W2f, W3f, b2, b3, temps, mask,
                                         (float*)d_out);
}

// Round 8
// 109.434 us; speedup vs baseline: 1.0444x; 1.0099x over previous
//
#include <hip/hip_runtime.h>
#include <math.h>

typedef _Float16 half8 __attribute__((ext_vector_type(8)));
typedef _Float16 half4v __attribute__((ext_vector_type(4)));
typedef float floatx4 __attribute__((ext_vector_type(4)));

// ---------------------------------------------------------------------------
// Prep: hih = (f16)(E@W1a + b1), hjh = (f16)(E@W1b); W2/W3 pre-swizzled into
// MFMA fragment order. blocks 0..255: four (b,s) rows each. block 256:
// W2frag. block 257: W3frag.
// ---------------------------------------------------------------------------
__global__ __launch_bounds__(256) void prep_kernel(
    const float* __restrict__ E,
    const float* __restrict__ W1,
    const float* __restrict__ b1,
    const float* __restrict__ W2,
    const float* __restrict__ W3,
    _Float16* __restrict__ hih,
    _Float16* __restrict__ hjh,
    _Float16* __restrict__ W2frag,
    _Float16* __restrict__ W3frag)
{
    const int blk = blockIdx.x;
    const int t = threadIdx.x;
    if (blk < 256) {
        __shared__ float sE[4][128];
        const int r0 = blk * 4;
        for (int e = t; e < 512; e += 256)
            sE[e >> 7][e & 127] = E[r0*128 + e];
        __syncthreads();
        const int half = t >> 7;       // 0: hi (with b1), 1: hj
        const int k = t & 127;
        float a0 = half ? 0.f : b1[k];
        float a1 = a0, a2 = a0, a3 = a0;
        const float* w1col = &W1[half*128*128 + k];
        #pragma unroll 8
        for (int d = 0; d < 128; ++d) {
            const float w = w1col[d*128];
            a0 = fmaf(sE[0][d], w, a0);
            a1 = fmaf(sE[1][d], w, a1);
            a2 = fmaf(sE[2][d], w, a2);
            a3 = fmaf(sE[3][d], w, a3);
        }
        _Float16* dst = half ? hjh : hih;
        dst[(r0+0)*128 + k] = (_Float16)a0;
        dst[(r0+1)*128 + k] = (_Float16)a1;
        dst[(r0+2)*128 + k] = (_Float16)a2;
        dst[(r0+3)*128 + k] = (_Float16)a3;
    } else if (blk == 256) {
        // A-frag order: frag g=((wr*4+nt)*4+ks), lane l, elem q holds
        // W2t[n][k]=W2[k][n], n=64*wr+16*nt+(l&15), k=ks*32+(l>>4)*8+q
        for (int e = t; e < 16384; e += 256) {
            int q = e & 7, l = (e >> 3) & 63, g = e >> 9;
            int wr = g >> 4, nt = (g >> 2) & 3, ks = g & 3;
            int row = 64*wr + 16*nt + (l & 15);
            int k = ks*32 + (l >> 4)*8 + q;
            W2frag[e] = (_Float16)W2[k*128 + row];
        }
    } else {
        // B-frag order: frag ks, lane l, elem q holds W3[k][n2],
        // n2=l&15, k=ks*32+(l>>4)*8+q
        for (int e = t; e < 2048; e += 256) {
            int q = e & 7, l = (e >> 3) & 63, ks = e >> 9;
            int k = ks*32 + (l >> 4)*8 + q;
            W3frag[e] = (_Float16)W3[k*16 + (l & 15)];
        }
    }
}

// ---------------------------------------------------------------------------
// Main: one block = (b, i0..i0+7, j0..j0+127), 512 blocks, 2/CU. Per i:
// GEMM1 -> each wave writes relu(D+b2) DIRECTLY IN GEMM2 A-FRAGMENT ORDER
// into a PRIVATE 8KB LDS region (no cross-wave data, no barrier) -> GEMM2
// partial over the wave's own n-half (reads own region, lgkmcnt only) ->
// wr=1 waves deposit 4KB f32 partials (ping-pong buffer), ONE barrier,
// wr=0 waves reduce + masked epilogue (nontemporal) while wr=1 waves race
// ahead into the next i's GEMM1. LDS = 32(sHJ)+32(frag)+16(partial) = 80KB
// = exactly 2 blocks/CU.
// Frag-order mapping (derived): source acc[nt][mt] reg r on lane (lr,lq)
// holds H2[m=64wc+16mt+lr][k=64wr+16nt+4lq+r]; in A-frag (mt,ks=nt>>1) this
// sits at lane (lr + 16*(2*(nt&1)+(lq>>1))), q = 4*(lq&1)+r -> the 4 regs
// form one contiguous b64 write.
// ---------------------------------------------------------------------------
__device__ __forceinline__ int swz(int row, int chunk) {
    // half-index of the 16B chunk base inside a [128][128] f16 tile
    return row*128 + ((chunk ^ (row & 7)) << 3);
}

__global__ __launch_bounds__(256, 2) void main_kernel(
    const _Float16* __restrict__ hih,
    const _Float16* __restrict__ hjh,
    const _Float16* __restrict__ W2frag,
    const _Float16* __restrict__ W3frag,
    const float* __restrict__ b2,
    const float* __restrict__ b3,
    const float* __restrict__ temps,
    const int* __restrict__ mask,
    float* __restrict__ out)
{
    __shared__ __align__(16) _Float16 sHJ[128 * 128];   // 32KB raw hj tile
    __shared__ __align__(16) _Float16 sFrag[4 * 4096];  // 32KB per-wave A-frags
    __shared__ __align__(16) float    sPart[2][2048];   // 16KB ping-pong partials

    const int tid = threadIdx.x;
    const int bid = blockIdx.x;
    const int b  = bid >> 8;                 // 2 x 64 x 4 = 512 blocks
    const int i0 = ((bid >> 2) & 63) << 3;   // 8 i's per block
    const int j0 = (bid & 3) << 7;

    const int lane = tid & 63;
    const int wave = tid >> 6;
    const int wr = wave >> 1;   // n-half owner
    const int wc = wave & 1;    // m-strip (j)
    const int lr = lane & 15;
    const int lq = lane >> 4;

    const half8 zero8 = {};
    const _Float16* hirow = &hih[(b*512 + i0)*128];
    const _Float16* hjbase = &hjh[(b*512 + j0)*128];
    const half8* w2v = (const half8*)W2frag;
    const half8* w3v = (const half8*)W3frag;

    // W2 A-fragments straight to registers (16 x b128, L2-hot), once per block
    half8 aW[4][4];
    #pragma unroll
    for (int nt = 0; nt < 4; ++nt)
        #pragma unroll
        for (int ks = 0; ks < 4; ++ks)
            aW[nt][ks] = w2v[((wr*4 + nt)*4 + ks)*64 + lane];

    // W3 B-fragments for this wave's n-half only (named regs, no dyn index)
    half8 w3A = w3v[(2*wr + 0)*64 + lane];
    half8 w3B = w3v[(2*wr + 1)*64 + lane];

    // b2 bias vectors (n-dependent only), once per block
    float4 bv[4];
    #pragma unroll
    for (int nt = 0; nt < 4; ++nt)
        bv[nt] = *(const float4*)&b2[64*wr + 16*nt + 4*lq];

    // hi fragments for i0
    half8 hiF[4];
    #pragma unroll
    for (int ks = 0; ks < 4; ++ks)
        hiF[ks] = *(const half8*)&hirow[ks*32 + lq*8];

    // epilogue constants (n2 = lr plane)
    const float tempv = temps[lr];
    const float b3v = b3[lr];

    // frag-write lane targets (constant per thread)
    _Float16* myfrag = &sFrag[wave*4096];
    const int tl_lo = lr + 16*(lq >> 1);   // nt even
    const int tl_hi = tl_lo + 32;          // nt odd
    const int foff = (lq & 1) * 4;

    // Stage raw hj tile once: 2048 16B-chunks, lane-contiguous, swizzled dest
    #pragma unroll
    for (int kk = 0; kk < 8; ++kk) {
        const int c = kk*256 + tid;       // chunk id
        const int row = c >> 4, col = c & 15;
        half8 v = *(const half8*)&hjbase[row*128 + col*8];
        *(half8*)&sHJ[swz(row, col)] = v;
    }
    __syncthreads();

    for (int ii = 0; ii < 8; ++ii) {
        const int i = i0 + ii;

        // GEMM1': D[n][m] = sum_k W2[k][n] * relu(hi[k]+hj[m][k])
        floatx4 acc[4][4] = {};
        #pragma unroll
        for (int ks = 0; ks < 4; ++ks) {
            half8 bF[4];
            #pragma unroll
            for (int mt = 0; mt < 4; ++mt) {
                const int m = 64*wc + 16*mt + lr;
                half8 hj8 = *(const half8*)&sHJ[swz(m, ks*4 + lq)];
                bF[mt] = __builtin_elementwise_max(hiF[ks] + hj8, zero8);
            }
            #pragma unroll
            for (int nt = 0; nt < 4; ++nt)
                #pragma unroll
                for (int mt = 0; mt < 4; ++mt)
                    acc[nt][mt] = __builtin_amdgcn_mfma_f32_16x16x32_f16(
                        aW[nt][ks], bF[mt], acc[nt][mt], 0, 0, 0);
        }

        // Prefetch next i's hi fragments
        {
            const _Float16* hin = &hirow[((ii < 7) ? (ii + 1) : ii)*128];
            #pragma unroll
            for (int ks = 0; ks < 4; ++ks)
                hiF[ks] = *(const half8*)&hin[ks*32 + lq*8];
        }

        // relu(D+b2) -> PRIVATE region, directly in GEMM2 A-frag order (b64)
        #pragma unroll
        for (int nt = 0; nt < 4; ++nt) {
            const int tl = (nt & 1) ? tl_hi : tl_lo;
            #pragma unroll
            for (int mt = 0; mt < 4; ++mt) {
                floatx4 v = acc[nt][mt];
                half4v o;
                o[0] = (_Float16)fmaxf(v[0] + bv[nt].x, 0.f);
                o[1] = (_Float16)fmaxf(v[1] + bv[nt].y, 0.f);
                o[2] = (_Float16)fmaxf(v[2] + bv[nt].z, 0.f);
                o[3] = (_Float16)fmaxf(v[3] + bv[nt].w, 0.f);
                *(half4v*)&myfrag[(mt*2 + (nt >> 1))*512 + tl*8 + foff] = o;
            }
        }

        // GEMM2 partial over own n-half: reads OWN region (no barrier needed)
        floatx4 acc2[4] = {};
        #pragma unroll
        for (int mt = 0; mt < 4; ++mt) {
            half8 a0 = *(const half8*)&myfrag[(mt*2 + 0)*512 + lane*8];
            half8 a1 = *(const half8*)&myfrag[(mt*2 + 1)*512 + lane*8];
            acc2[mt] = __builtin_amdgcn_mfma_f32_16x16x32_f16(a0, w3A, acc2[mt], 0, 0, 0);
            acc2[mt] = __builtin_amdgcn_mfma_f32_16x16x32_f16(a1, w3B, acc2[mt], 0, 0, 0);
        }

        float* pp = sPart[ii & 1];
        int4 mk[4];
        if (wr == 1) {
            // deposit partial (m-strip wc, n-half hi) for the wr=0 partner
            #pragma unroll
            for (int mt = 0; mt < 4; ++mt)
                *(floatx4*)&pp[wc*1024 + mt*256 + lane*4] = acc2[mt];
        } else {
            // prefetch mask rows for this i while partials land
            const int* mrow = &mask[(b*512 + i)*512];
            #pragma unroll
            for (int mt = 0; mt < 4; ++mt)
                mk[mt] = *(const int4*)&mrow[j0 + 64*wc + 16*mt + 4*lq];
        }
        __syncthreads();   // the ONLY barrier per i

        if (wr == 0) {
            // reduce halves + epilogue for m-strip wc (64 rows)
            float* outp = &out[(((b*16 + lr)*512) + i)*512];
            #pragma unroll
            for (int mt = 0; mt < 4; ++mt) {
                floatx4 p = *(const floatx4*)&pp[wc*1024 + mt*256 + lane*4];
                floatx4 v = acc2[mt] + p;
                const int j = j0 + 64*wc + 16*mt + 4*lq;
                floatx4 res;
                res[0] = mk[mt].x ? (v[0] + b3v)*tempv : -INFINITY;
                res[1] = mk[mt].y ? (v[1] + b3v)*tempv : -INFINITY;
                res[2] = mk[mt].z ? (v[2] + b3v)*tempv : -INFINITY;
                res[3] = mk[mt].w ? (v[3] + b3v)*tempv : -INFINITY;
                __builtin_nontemporal_store(res, (floatx4*)&outp[j]);
            }
        }
        // wr=1 waves run ahead into next i's GEMM1; ping-pong (ii&1) + the
        // per-i barrier guarantee partials aren't overwritten before read.
    }
}

extern "C" void kernel_launch(void* const* d_in, const int* in_sizes, int n_in,
                              void* d_out, int out_size, void* d_ws, size_t ws_size,
                              hipStream_t stream)
{
    const float* E     = (const float*)d_in[0];
    const int* mask    = (const int*)d_in[1];
    const float* W1    = (const float*)d_in[2];
    const float* b1    = (const float*)d_in[3];
    const float* W2    = (const float*)d_in[4];
    const float* b2    = (const float*)d_in[5];
    const float* W3    = (const float*)d_in[6];
    const float* b3    = (const float*)d_in[7];
    const float* temps = (const float*)d_in[8];

    char* ws = (char*)d_ws;
    _Float16* hih = (_Float16*)ws;                       // 1024*128 f16 = 256KB
    _Float16* hjh = (_Float16*)(ws + 262144);            // 256KB
    _Float16* W2f = (_Float16*)(ws + 524288);            // 32KB
    _Float16* W3f = W2f + 16384;                         // 4KB

    prep_kernel<<<258, 256, 0, stream>>>(E, W1, b1, W2, W3, hih, hjh, W2f, W3f);
    main_kernel<<<512, 256, 0, stream>>>(hih, hjh, W2f, W3f, b2, b3, temps, mask,
                                         (float*)d_out);
}